// Round 5
// baseline (443.922 us; speedup 1.0000x reference)
//
#include <hip/hip_runtime.h>
#include <hip/hip_fp16.h>
#include <cstdint>
#include <cstddef>

#define B_ 4
#define S_ 4096
#define D_ 1024
#define E_ 1536
#define M_ (B_*S_)       // 16384
#define BE_ (B_*E_)      // 6144
#define C_ 32            // scan chunks
#define L_ (S_/C_)       // 128

typedef short bf16x8 __attribute__((ext_vector_type(8)));
typedef float f32x4 __attribute__((ext_vector_type(4)));

__device__ __forceinline__ unsigned short f2b(float f) {
  union { float f; unsigned int i; } x; x.f = f;
  unsigned int r = x.i + 0x7FFFu + ((x.i >> 16) & 1u);   // RNE
  return (unsigned short)(r >> 16);
}
__device__ __forceinline__ float h2f(unsigned short u) { return __half2float(__ushort_as_half(u)); }
__device__ __forceinline__ unsigned int packcv(float c, float v) {
  return (unsigned int)__half_as_ushort(__float2half_rn(c)) |
         ((unsigned int)__half_as_ushort(__float2half_rn(v)) << 16);
}
// async global->LDS, 16B per lane; LDS dest = wave-uniform base + lane*16
__device__ __forceinline__ void async16(const unsigned short* g, unsigned short* l) {
  __builtin_amdgcn_global_load_lds((const __attribute__((address_space(1))) unsigned int*)g,
                                   (__attribute__((address_space(3))) unsigned int*)l, 16, 0, 0);
}

// ---------- fp32 -> bf16 conversion ----------
__global__ __launch_bounds__(256) void cvt_bf16(const float* __restrict__ src,
                                                unsigned short* __restrict__ dst) {
  const int i = blockIdx.x * 256 + threadIdx.x;
  float4 f = ((const float4*)src)[i];
  ushort4 u; u.x = f2b(f.x); u.y = f2b(f.y); u.z = f2b(f.z); u.w = f2b(f.w);
  ((ushort4*)dst)[i] = u;
}

// ---------- GEMM1 (MFMA bf16, async staging) fused with gate pointwise ----------
// tile: 128 m x 64 e (B tile = 64 h-rows + 64 g-rows of W_hg). 4 waves, each 64m x 32e x {h,g}.
__global__ __launch_bounds__(256) void gemm1_mfma(const unsigned short* __restrict__ Xb,
                                                  const unsigned short* __restrict__ Wb,
                                                  unsigned int* __restrict__ CV) {
  __shared__ unsigned short lA[128 * 32];
  __shared__ unsigned short lB[128 * 32];
  const int t = threadIdx.x;
  const int m0 = blockIdx.x * 128;
  const int n0 = blockIdx.y * 64;
  const int wv = t >> 6, lane = t & 63;
  const int wm = wv >> 1, we = wv & 1;
  const int lm = lane & 15, kg = lane >> 4;
  const int lrow = lane >> 2, lq = lane & 3;   // staging: row-in-chunk, 16B col chunk

  const f32x4 z4 = {0.f, 0.f, 0.f, 0.f};
  f32x4 ah[4][2], ag[4][2];
#pragma unroll
  for (int i = 0; i < 4; ++i)
#pragma unroll
    for (int j = 0; j < 2; ++j) { ah[i][j] = z4; ag[i][j] = z4; }

  for (int k0 = 0; k0 < D_; k0 += 32) {
    // 16 chunks of 1KB (16 rows x 64B); wave wv issues chunks 4wv..4wv+3
#pragma unroll
    for (int j = 0; j < 4; ++j) {
      const int c = (wv << 2) | j;
      if (c < 8) {
        const int row = c * 16 + lrow;
        async16(Xb + (size_t)(m0 + row) * D_ + k0 + lq * 8, lA + (size_t)c * 512);
      } else {
        const int row = (c - 8) * 16 + lrow;   // 0..127 in B tile
        const int gr = (row < 64) ? (n0 + row) : (E_ + n0 + row - 64);
        async16(Wb + (size_t)gr * D_ + k0 + lq * 8, lB + (size_t)(c - 8) * 512);
      }
    }
    __syncthreads();
    bf16x8 af[4], bh[2], bg[2];
#pragma unroll
    for (int mt = 0; mt < 4; ++mt)
      af[mt] = *(const bf16x8*)(lA + (size_t)(wm * 64 + mt * 16 + lm) * 32 + kg * 8);
#pragma unroll
    for (int et = 0; et < 2; ++et) {
      bh[et] = *(const bf16x8*)(lB + (size_t)(we * 32 + et * 16 + lm) * 32 + kg * 8);
      bg[et] = *(const bf16x8*)(lB + (size_t)(64 + we * 32 + et * 16 + lm) * 32 + kg * 8);
    }
#pragma unroll
    for (int mt = 0; mt < 4; ++mt)
#pragma unroll
      for (int et = 0; et < 2; ++et) {
        ah[mt][et] = __builtin_amdgcn_mfma_f32_16x16x32_bf16(af[mt], bh[et], ah[mt][et], 0, 0, 0);
        ag[mt][et] = __builtin_amdgcn_mfma_f32_16x16x32_bf16(af[mt], bg[et], ag[mt][et], 0, 0, 0);
      }
    __syncthreads();
  }
  // epilogue: C/D layout col=lane&15, row=kg*4+reg
#pragma unroll
  for (int mt = 0; mt < 4; ++mt)
#pragma unroll
    for (int et = 0; et < 2; ++et) {
      const int e = n0 + we * 32 + et * 16 + lm;
#pragma unroll
      for (int r = 0; r < 4; ++r) {
        const int m = m0 + wm * 64 + mt * 16 + kg * 4 + r;
        const float hid = ah[mt][et][r];
        const float gat = ag[mt][et][r];
        const float z = 1.f / (1.f + expf(-gat));
        const float c = 1.f / (1.f + expf(gat));
        const float gv = (hid >= 0.f) ? (hid + 0.5f) : (1.f / (1.f + expf(-hid)));
        CV[(size_t)m * E_ + e] = packcv(c, z * gv);
      }
    }
}

// ---------- scan pass 1: per-chunk (P, Qf, Qr), 2 e-columns per thread ----------
__global__ __launch_bounds__(256) void scan_p1(const uint2* __restrict__ CV2,
                                               float2* __restrict__ P2, float2* __restrict__ Qf2,
                                               float2* __restrict__ Qr2) {
  const int pe = blockIdx.x * 256 + threadIdx.x;        // 0..BE_/2-1
  const int b = pe / (E_ / 2), e2 = pe - b * (E_ / 2);
  const int k = blockIdx.y;
  const uint2* cv = CV2 + ((size_t)b * S_ + (size_t)k * L_) * (E_ / 2) + e2;
  float pp0 = 1.f, qf0 = 0.f, qr0 = 0.f;
  float pp1 = 1.f, qf1 = 0.f, qr1 = 0.f;
#pragma unroll 8
  for (int l = 0; l < L_; ++l) {
    const uint2 p = cv[(size_t)l * (E_ / 2)];
    const float c0 = h2f((unsigned short)p.x), v0 = h2f((unsigned short)(p.x >> 16));
    const float c1 = h2f((unsigned short)p.y), v1 = h2f((unsigned short)(p.y >> 16));
    qf0 = fmaf(c0, qf0, v0); qr0 = fmaf(pp0, v0, qr0); pp0 *= c0;
    qf1 = fmaf(c1, qf1, v1); qr1 = fmaf(pp1, v1, qr1); pp1 *= c1;
  }
  const size_t o = (size_t)k * (BE_ / 2) + pe;
  P2[o]  = make_float2(pp0, pp1);
  Qf2[o] = make_float2(qf0, qf1);
  Qr2[o] = make_float2(qr0, qr1);
}

// ---------- scan pass 2: chunk-level prefix (tiny) ----------
__global__ __launch_bounds__(256) void scan_p2(const float* __restrict__ P, const float* __restrict__ Qf,
                                               const float* __restrict__ Qr, float* __restrict__ HfIn,
                                               float* __restrict__ HbIn) {
  const int be = blockIdx.x * 256 + threadIdx.x;
  float hf = 0.f;
  for (int k = 0; k < C_; ++k) {
    HfIn[(size_t)k * BE_ + be] = hf;
    hf = fmaf(P[(size_t)k * BE_ + be], hf, Qf[(size_t)k * BE_ + be]);
  }
  float hb = 0.f;
  for (int k = C_ - 1; k >= 0; --k) {
    HbIn[(size_t)k * BE_ + be] = hb;   // state after consuming original chunks > k
    hb = fmaf(P[(size_t)k * BE_ + be], hb, Qr[(size_t)k * BE_ + be]);
  }
}

// ---------- scan pass 3: replay with carry-ins, write H = hf + hb (bf16) ----------
__global__ __launch_bounds__(256) void scan_p3(const uint2* __restrict__ CV2,
                                               const float2* __restrict__ HfIn2,
                                               const float2* __restrict__ HbIn2,
                                               unsigned int* __restrict__ Hb2) {
  const int pe = blockIdx.x * 256 + threadIdx.x;
  const int b = pe / (E_ / 2), e2 = pe - b * (E_ / 2);
  const int k = blockIdx.y;                    // output chunk
  const uint2* cvf = CV2 + ((size_t)b * S_ + (size_t)k * L_) * (E_ / 2) + e2;
  const uint2* cvb = CV2 + ((size_t)b * S_ + (size_t)(S_ - 1 - k * L_)) * (E_ / 2) + e2;
  unsigned int* hp = Hb2 + ((size_t)b * S_ + (size_t)k * L_) * (E_ / 2) + e2;
  const float2 f0 = HfIn2[(size_t)k * (BE_ / 2) + pe];
  const float2 b0 = HbIn2[(size_t)(C_ - 1 - k) * (BE_ / 2) + pe];
  float hf0 = f0.x, hf1 = f0.y, hb0 = b0.x, hb1 = b0.y;
#pragma unroll 8
  for (int l = 0; l < L_; ++l) {
    const uint2 pf = cvf[(size_t)l * (E_ / 2)];
    const uint2 pb = *(cvb - (ptrdiff_t)l * (E_ / 2));
    hf0 = fmaf(h2f((unsigned short)pf.x), hf0, h2f((unsigned short)(pf.x >> 16)));
    hf1 = fmaf(h2f((unsigned short)pf.y), hf1, h2f((unsigned short)(pf.y >> 16)));
    hb0 = fmaf(h2f((unsigned short)pb.x), hb0, h2f((unsigned short)(pb.x >> 16)));
    hb1 = fmaf(h2f((unsigned short)pb.y), hb1, h2f((unsigned short)(pb.y >> 16)));
    hp[(size_t)l * (E_ / 2)] = (unsigned int)f2b(hf0 + hb0) | ((unsigned int)f2b(hf1 + hb1) << 16);
  }
}

// ---------- GEMM2 (MFMA bf16, async staging): out[m,d] = sum_e H[m,e]*Wo[d,e] ----------
// tile 128 m x 128 d, 4 waves each 64x64.
__global__ __launch_bounds__(256) void gemm2_mfma(const unsigned short* __restrict__ Hb,
                                                  const unsigned short* __restrict__ Wob,
                                                  float* __restrict__ Out) {
  __shared__ unsigned short lA[128 * 32];
  __shared__ unsigned short lB[128 * 32];
  const int t = threadIdx.x;
  const int m0 = blockIdx.x * 128;
  const int n0 = blockIdx.y * 128;
  const int wv = t >> 6, lane = t & 63;
  const int wm = wv >> 1, wn = wv & 1;
  const int lm = lane & 15, kg = lane >> 4;
  const int lrow = lane >> 2, lq = lane & 3;

  const f32x4 z4 = {0.f, 0.f, 0.f, 0.f};
  f32x4 acc[4][4];
#pragma unroll
  for (int i = 0; i < 4; ++i)
#pragma unroll
    for (int j = 0; j < 4; ++j) acc[i][j] = z4;

  for (int k0 = 0; k0 < E_; k0 += 32) {
#pragma unroll
    for (int j = 0; j < 4; ++j) {
      const int c = (wv << 2) | j;
      if (c < 8) {
        const int row = c * 16 + lrow;
        async16(Hb + (size_t)(m0 + row) * E_ + k0 + lq * 8, lA + (size_t)c * 512);
      } else {
        const int row = (c - 8) * 16 + lrow;
        async16(Wob + (size_t)(n0 + row) * E_ + k0 + lq * 8, lB + (size_t)(c - 8) * 512);
      }
    }
    __syncthreads();
    bf16x8 af[4], bf[4];
#pragma unroll
    for (int mt = 0; mt < 4; ++mt)
      af[mt] = *(const bf16x8*)(lA + (size_t)(wm * 64 + mt * 16 + lm) * 32 + kg * 8);
#pragma unroll
    for (int nt = 0; nt < 4; ++nt)
      bf[nt] = *(const bf16x8*)(lB + (size_t)(wn * 64 + nt * 16 + lm) * 32 + kg * 8);
#pragma unroll
    for (int mt = 0; mt < 4; ++mt)
#pragma unroll
      for (int nt = 0; nt < 4; ++nt)
        acc[mt][nt] = __builtin_amdgcn_mfma_f32_16x16x32_bf16(af[mt], bf[nt], acc[mt][nt], 0, 0, 0);
    __syncthreads();
  }
#pragma unroll
  for (int mt = 0; mt < 4; ++mt)
#pragma unroll
    for (int nt = 0; nt < 4; ++nt) {
      const int d = n0 + wn * 64 + nt * 16 + lm;
#pragma unroll
      for (int r = 0; r < 4; ++r) {
        const int m = m0 + wm * 64 + mt * 16 + kg * 4 + r;
        Out[(size_t)m * D_ + d] = acc[mt][nt][r];
      }
    }
}

extern "C" void kernel_launch(void* const* d_in, const int* in_sizes, int n_in,
                              void* d_out, int out_size, void* d_ws, size_t ws_size,
                              hipStream_t stream) {
  const float* x    = (const float*)d_in[0];   // [4,4096,1024] fp32
  const float* whg  = (const float*)d_in[1];   // [3072,1024]  fp32
  const float* wout = (const float*)d_in[2];   // [1024,1536]  fp32
  float* out = (float*)d_out;                  // [4,4096,1024] fp32

  // ws (151 MB, proven-safe): [CV: M*E*4][H: M*E*2]
  unsigned int*  CV = (unsigned int*)d_ws;
  unsigned short* Hb = (unsigned short*)((char*)d_ws + (size_t)M_ * E_ * 4);
  // phase-overlapped aliases:
  unsigned short* Xb  = Hb;                     // bf16 X in H region until scan writes H
  unsigned short* Wb  = Xb + (size_t)M_ * D_;   // bf16 W_hg after it
  unsigned short* Wob = (unsigned short*)d_ws;  // bf16 W_out in CV region (CV dead after scan)
  // scan chunk scratch lives in d_out (gemm2 fully overwrites it afterwards)
  float* P    = out;
  float* Qf   = out + (size_t)C_ * BE_;
  float* Qr   = out + 2 * (size_t)C_ * BE_;
  float* HfIn = out + 3 * (size_t)C_ * BE_;
  float* HbIn = out + 4 * (size_t)C_ * BE_;

  cvt_bf16<<<M_ * D_ / 1024, 256, 0, stream>>>(x, Xb);
  cvt_bf16<<<2 * E_ * D_ / 1024, 256, 0, stream>>>(whg, Wb);
  gemm1_mfma<<<dim3(M_ / 128, E_ / 64), 256, 0, stream>>>(Xb, Wb, CV);
  scan_p1<<<dim3(BE_ / 512, C_), 256, 0, stream>>>((const uint2*)CV, (float2*)P, (float2*)Qf, (float2*)Qr);
  scan_p2<<<BE_ / 256, 256, 0, stream>>>(P, Qf, Qr, HfIn, HbIn);
  scan_p3<<<dim3(BE_ / 512, C_), 256, 0, stream>>>((const uint2*)CV, (const float2*)HfIn,
                                                   (const float2*)HbIn, (unsigned int*)Hb);
  cvt_bf16<<<D_ * E_ / 1024, 256, 0, stream>>>(wout, Wob);
  gemm2_mfma<<<dim3(M_ / 128, D_ / 128), 256, 0, stream>>>(Hb, Wob, out);
}

// Round 7
// 400.238 us; speedup vs baseline: 1.1091x; 1.1091x over previous
//
#include <hip/hip_runtime.h>
#include <hip/hip_fp16.h>
#include <cstdint>
#include <cstddef>

#define B_ 4
#define S_ 4096
#define D_ 1024
#define E_ 1536
#define M_ (B_*S_)       // 16384
#define BE_ (B_*E_)      // 6144
#define C_ 32            // scan chunks
#define L_ (S_/C_)       // 128

typedef short bf16x8 __attribute__((ext_vector_type(8)));
typedef float f32x4 __attribute__((ext_vector_type(4)));

__device__ __forceinline__ unsigned short f2b(float f) {
  union { float f; unsigned int i; } x; x.f = f;
  unsigned int r = x.i + 0x7FFFu + ((x.i >> 16) & 1u);   // RNE
  return (unsigned short)(r >> 16);
}
__device__ __forceinline__ float h2f(unsigned short u) { return __half2float(__ushort_as_half(u)); }
__device__ __forceinline__ unsigned int packcv(float c, float v) {
  return (unsigned int)__half_as_ushort(__float2half_rn(c)) |
         ((unsigned int)__half_as_ushort(__float2half_rn(v)) << 16);
}
__device__ __forceinline__ void async16(const unsigned short* g, unsigned short* l) {
  __builtin_amdgcn_global_load_lds((const __attribute__((address_space(1))) unsigned int*)g,
                                   (__attribute__((address_space(3))) unsigned int*)l, 16, 0, 0);
}

// ---------- fp32 -> bf16 conversion, generic (1024 elems / block) ----------
__global__ __launch_bounds__(256) void cvt_bf16(const float* __restrict__ src,
                                                unsigned short* __restrict__ dst) {
  const int i = blockIdx.x * 256 + threadIdx.x;
  float4 f = ((const float4*)src)[i];
  ushort4 u; u.x = f2b(f.x); u.y = f2b(f.y); u.z = f2b(f.z); u.w = f2b(f.w);
  ((ushort4*)dst)[i] = u;
}

// ---------- fused conversion: x + W_hg (W_out must wait until CV is dead) ----------
#define NB_X   (M_*D_/1024)        // 16384 blocks
#define NB_WHG (2*E_*D_/1024)      // 3072
__global__ __launch_bounds__(256) void cvt_xw(const float* __restrict__ x, unsigned short* __restrict__ xb,
                                              const float* __restrict__ whg, unsigned short* __restrict__ wb) {
  int blk = blockIdx.x;
  const float* src; unsigned short* dst;
  if (blk < NB_X) { src = x; dst = xb; }
  else            { blk -= NB_X; src = whg; dst = wb; }
  const int i = blk * 256 + threadIdx.x;
  float4 f = ((const float4*)src)[i];
  ushort4 u; u.x = f2b(f.x); u.y = f2b(f.y); u.z = f2b(f.z); u.w = f2b(f.w);
  ((ushort4*)dst)[i] = u;
}

// ---------- GEMM1 (MFMA bf16, BK=64, async staging) + gate pointwise ----------
// tile: 128 m x 64 e; B tile = 64 h-rows + 64 g-rows. 4 waves: each 64m x 32e x {h,g}.
// Staging: waves 0,1 -> A half-tiles (rows wv*64..wv*64+63); waves 2,3 -> B (h / g half).
// Each wave: 8 chunks of 1KB (8 rows x 128B); lane -> row=lane>>3, 16B-col=lane&7;
// LDS dest base for chunk j = half_base + j*512 ushorts (contiguous lane*16B within chunk).
__global__ __launch_bounds__(256) void gemm1_mfma(const unsigned short* __restrict__ Xb,
                                                  const unsigned short* __restrict__ Wb,
                                                  unsigned int* __restrict__ CV) {
  __shared__ unsigned short lA[128 * 64];   // 16KB
  __shared__ unsigned short lB[128 * 64];   // 16KB
  const int t = threadIdx.x;
  const int m0 = blockIdx.x * 128;
  const int n0 = blockIdx.y * 64;
  const int wv = t >> 6, lane = t & 63;
  const int wm = wv >> 1, we = wv & 1;
  const int lm = lane & 15, kg = lane >> 4;
  const int srow = lane >> 3, scol = lane & 7;
  const bool stageA = (wv < 2);
  const unsigned short* gbase;
  if (stageA) {
    gbase = Xb + (size_t)(m0 + (wv * 64) + srow) * D_ + scol * 8;
  } else {
    const int rloc = (wv - 2) * 64 + srow;   // 0..7 -> h rows, 64..71 -> g rows
    const int gr = (rloc < 64) ? (n0 + rloc) : (E_ + n0 + rloc - 64);
    gbase = Wb + (size_t)gr * D_ + scol * 8;
  }
  // each wave's 64-row half = 64*64 = 4096 ushorts
  unsigned short* lbase = (stageA ? lA : lB) + (size_t)(wv & 1) * 4096;

  const f32x4 z4 = {0.f, 0.f, 0.f, 0.f};
  f32x4 ah[4][2], ag[4][2];
#pragma unroll
  for (int i = 0; i < 4; ++i)
#pragma unroll
    for (int j = 0; j < 2; ++j) { ah[i][j] = z4; ag[i][j] = z4; }

  for (int k0 = 0; k0 < D_; k0 += 64) {
#pragma unroll
    for (int j = 0; j < 8; ++j)
      async16(gbase + k0 + (size_t)(j * 8) * D_, lbase + (size_t)j * 512);
    __syncthreads();
#pragma unroll
    for (int kh = 0; kh < 2; ++kh) {
      bf16x8 af[4], bh[2], bg[2];
#pragma unroll
      for (int mt = 0; mt < 4; ++mt)
        af[mt] = *(const bf16x8*)(lA + (size_t)(wm * 64 + mt * 16 + lm) * 64 + kh * 32 + kg * 8);
#pragma unroll
      for (int et = 0; et < 2; ++et) {
        bh[et] = *(const bf16x8*)(lB + (size_t)(we * 32 + et * 16 + lm) * 64 + kh * 32 + kg * 8);
        bg[et] = *(const bf16x8*)(lB + (size_t)(64 + we * 32 + et * 16 + lm) * 64 + kh * 32 + kg * 8);
      }
#pragma unroll
      for (int mt = 0; mt < 4; ++mt)
#pragma unroll
        for (int et = 0; et < 2; ++et) {
          ah[mt][et] = __builtin_amdgcn_mfma_f32_16x16x32_bf16(af[mt], bh[et], ah[mt][et], 0, 0, 0);
          ag[mt][et] = __builtin_amdgcn_mfma_f32_16x16x32_bf16(af[mt], bg[et], ag[mt][et], 0, 0, 0);
        }
    }
    __syncthreads();
  }
  // epilogue: C/D layout col=lane&15, row=kg*4+reg ; fast-exp sigmoids, c = 1-z
#pragma unroll
  for (int mt = 0; mt < 4; ++mt)
#pragma unroll
    for (int et = 0; et < 2; ++et) {
      const int e = n0 + we * 32 + et * 16 + lm;
#pragma unroll
      for (int r = 0; r < 4; ++r) {
        const int m = m0 + wm * 64 + mt * 16 + kg * 4 + r;
        const float hid = ah[mt][et][r];
        const float gat = ag[mt][et][r];
        const float z = 1.f / (1.f + __expf(-gat));
        const float c = 1.f - z;
        const float gv = (hid >= 0.f) ? (hid + 0.5f) : (1.f / (1.f + __expf(-hid)));
        CV[(size_t)m * E_ + e] = packcv(c, z * gv);
      }
    }
}

// ---------- scan pass 1: per-chunk (P, Qf, Qr) ----------
__global__ __launch_bounds__(256) void scan_p1(const unsigned int* __restrict__ CV,
                                               float* __restrict__ P, float* __restrict__ Qf,
                                               float* __restrict__ Qr) {
  const int be = blockIdx.x * 256 + threadIdx.x;
  const int b = be / E_, e = be - b * E_;
  const int k = blockIdx.y;
  const unsigned int* cv = CV + ((size_t)b * S_ + (size_t)k * L_) * E_ + e;
  float pp = 1.f, qf = 0.f, qr = 0.f;
#pragma unroll 8
  for (int l = 0; l < L_; ++l) {
    const unsigned int p = cv[(size_t)l * E_];
    const float c = h2f((unsigned short)p), v = h2f((unsigned short)(p >> 16));
    qf = fmaf(c, qf, v);
    qr = fmaf(pp, v, qr);
    pp *= c;
  }
  P[(size_t)k * BE_ + be] = pp;
  Qf[(size_t)k * BE_ + be] = qf;
  Qr[(size_t)k * BE_ + be] = qr;
}

// ---------- scan pass 2: chunk-level prefix (tiny) ----------
__global__ __launch_bounds__(256) void scan_p2(const float* __restrict__ P, const float* __restrict__ Qf,
                                               const float* __restrict__ Qr, float* __restrict__ HfIn,
                                               float* __restrict__ HbIn) {
  const int be = blockIdx.x * 256 + threadIdx.x;
  float hf = 0.f;
  for (int k = 0; k < C_; ++k) {
    HfIn[(size_t)k * BE_ + be] = hf;
    hf = fmaf(P[(size_t)k * BE_ + be], hf, Qf[(size_t)k * BE_ + be]);
  }
  float hb = 0.f;
  for (int k = C_ - 1; k >= 0; --k) {
    HbIn[(size_t)k * BE_ + be] = hb;   // state after consuming original chunks > k
    hb = fmaf(P[(size_t)k * BE_ + be], hb, Qr[(size_t)k * BE_ + be]);
  }
}

// ---------- scan pass 3: replay with carry-ins, write H = hf + hb (bf16) ----------
__global__ __launch_bounds__(256) void scan_p3(const unsigned int* __restrict__ CV,
                                               const float* __restrict__ HfIn,
                                               const float* __restrict__ HbIn,
                                               unsigned short* __restrict__ Hb) {
  const int be = blockIdx.x * 256 + threadIdx.x;
  const int b = be / E_, e = be - b * E_;
  const int k = blockIdx.y;
  const unsigned int* cvf = CV + ((size_t)b * S_ + (size_t)k * L_) * E_ + e;
  const unsigned int* cvb = CV + ((size_t)b * S_ + (size_t)(S_ - 1 - k * L_)) * E_ + e;
  unsigned short* hp = Hb + ((size_t)b * S_ + (size_t)k * L_) * E_ + e;
  float hf = HfIn[(size_t)k * BE_ + be];
  float hb = HbIn[(size_t)(C_ - 1 - k) * BE_ + be];
#pragma unroll 8
  for (int l = 0; l < L_; ++l) {
    const unsigned int pf = cvf[(size_t)l * E_];
    const unsigned int pb = *(cvb - (ptrdiff_t)l * E_);
    hf = fmaf(h2f((unsigned short)pf), hf, h2f((unsigned short)(pf >> 16)));
    hb = fmaf(h2f((unsigned short)pb), hb, h2f((unsigned short)(pb >> 16)));
    hp[(size_t)l * E_] = f2b(hf + hb);
  }
}

// ---------- GEMM2 (MFMA bf16, async staging): out[m,d] = sum_e H[m,e]*Wo[d,e] ----------
__global__ __launch_bounds__(256) void gemm2_mfma(const unsigned short* __restrict__ Hb,
                                                  const unsigned short* __restrict__ Wob,
                                                  float* __restrict__ Out) {
  __shared__ unsigned short lA[128 * 32];
  __shared__ unsigned short lB[128 * 32];
  const int t = threadIdx.x;
  const int m0 = blockIdx.x * 128;
  const int n0 = blockIdx.y * 128;
  const int wv = t >> 6, lane = t & 63;
  const int wm = wv >> 1, wn = wv & 1;
  const int lm = lane & 15, kg = lane >> 4;
  const int lrow = lane >> 2, lq = lane & 3;

  const f32x4 z4 = {0.f, 0.f, 0.f, 0.f};
  f32x4 acc[4][4];
#pragma unroll
  for (int i = 0; i < 4; ++i)
#pragma unroll
    for (int j = 0; j < 4; ++j) acc[i][j] = z4;

  for (int k0 = 0; k0 < E_; k0 += 32) {
#pragma unroll
    for (int j = 0; j < 4; ++j) {
      const int c = (wv << 2) | j;
      if (c < 8) {
        const int row = c * 16 + lrow;
        async16(Hb + (size_t)(m0 + row) * E_ + k0 + lq * 8, lA + (size_t)c * 512);
      } else {
        const int row = (c - 8) * 16 + lrow;
        async16(Wob + (size_t)(n0 + row) * E_ + k0 + lq * 8, lB + (size_t)(c - 8) * 512);
      }
    }
    __syncthreads();
    bf16x8 af[4], bf[4];
#pragma unroll
    for (int mt = 0; mt < 4; ++mt)
      af[mt] = *(const bf16x8*)(lA + (size_t)(wm * 64 + mt * 16 + lm) * 32 + kg * 8);
#pragma unroll
    for (int nt = 0; nt < 4; ++nt)
      bf[nt] = *(const bf16x8*)(lB + (size_t)(wn * 64 + nt * 16 + lm) * 32 + kg * 8);
#pragma unroll
    for (int mt = 0; mt < 4; ++mt)
#pragma unroll
      for (int nt = 0; nt < 4; ++nt)
        acc[mt][nt] = __builtin_amdgcn_mfma_f32_16x16x32_bf16(af[mt], bf[nt], acc[mt][nt], 0, 0, 0);
    __syncthreads();
  }
#pragma unroll
  for (int mt = 0; mt < 4; ++mt)
#pragma unroll
    for (int nt = 0; nt < 4; ++nt) {
      const int d = n0 + wn * 64 + nt * 16 + lm;
#pragma unroll
      for (int r = 0; r < 4; ++r) {
        const int m = m0 + wm * 64 + mt * 16 + kg * 4 + r;
        Out[(size_t)m * D_ + d] = acc[mt][nt][r];
      }
    }
}

extern "C" void kernel_launch(void* const* d_in, const int* in_sizes, int n_in,
                              void* d_out, int out_size, void* d_ws, size_t ws_size,
                              hipStream_t stream) {
  const float* x    = (const float*)d_in[0];
  const float* whg  = (const float*)d_in[1];
  const float* wout = (const float*)d_in[2];
  float* out = (float*)d_out;

  // ws (151 MB, proven-safe): [CV: M*E*4][H: M*E*2]
  unsigned int*  CV = (unsigned int*)d_ws;
  unsigned short* Hb = (unsigned short*)((char*)d_ws + (size_t)M_ * E_ * 4);
  unsigned short* Xb  = Hb;                     // bf16 X in H region until scan writes H
  unsigned short* Wb  = Xb + (size_t)M_ * D_;
  unsigned short* Wob = (unsigned short*)d_ws;  // bf16 W_out in CV region — ONLY after scans done
  // scan chunk scratch in d_out (gemm2 fully overwrites)
  float* P    = out;
  float* Qf   = out + (size_t)C_ * BE_;
  float* Qr   = out + 2 * (size_t)C_ * BE_;
  float* HfIn = out + 3 * (size_t)C_ * BE_;
  float* HbIn = out + 4 * (size_t)C_ * BE_;

  cvt_xw<<<NB_X + NB_WHG, 256, 0, stream>>>(x, Xb, whg, Wb);
  gemm1_mfma<<<dim3(M_ / 128, E_ / 64), 256, 0, stream>>>(Xb, Wb, CV);
  scan_p1<<<dim3(BE_ / 256, C_), 256, 0, stream>>>(CV, P, Qf, Qr);
  scan_p2<<<BE_ / 256, 256, 0, stream>>>(P, Qf, Qr, HfIn, HbIn);
  scan_p3<<<dim3(BE_ / 256, C_), 256, 0, stream>>>(CV, HfIn, HbIn, Hb);
  cvt_bf16<<<D_ * E_ / 1024, 256, 0, stream>>>(wout, Wob);   // CV dead now
  gemm2_mfma<<<dim3(M_ / 128, D_ / 128), 256, 0, stream>>>(Hb, Wob, out);
}